// Round 13
// baseline (157.095 us; speedup 1.0000x reference)
//
#include <hip/hip_runtime.h>
#include <stdint.h>

typedef unsigned short u16;
typedef float f32x4 __attribute__((ext_vector_type(4)));
typedef short short8 __attribute__((ext_vector_type(8)));
typedef unsigned uint4v __attribute__((ext_vector_type(4)));

enum { NT = 65536, KC = 2048, D = 128, H = 256, A_DIM = 6 };

__device__ __forceinline__ u16 f2bf(float f) {
    union { float f; unsigned u; } x; x.f = f;
    unsigned r = x.u + 0x7FFFu + ((x.u >> 16) & 1u);
    return (u16)(r >> 16);
}
__device__ __forceinline__ float bf2f(u16 u) {
    union { unsigned u; float f; } x; x.u = ((unsigned)u) << 16;
    return x.f;
}

typedef __attribute__((address_space(1))) void gvoid;
typedef __attribute__((address_space(3))) void lvoid;
__device__ __forceinline__ void gload_lds16(const void* g, void* l) {
    __builtin_amdgcn_global_load_lds((gvoid*)g, (lvoid*)l, 16, 0, 0);
}

// ---------------- prep: transpose+cast weights to bf16 [N][K], cast emb, emb row norms, zero sums
__global__ void prep(const float* __restrict__ W_e2, const float* __restrict__ W_e3,
                     const float* __restrict__ W_d1, const float* __restrict__ W_d2,
                     const float* __restrict__ emb,
                     u16* __restrict__ We2T, u16* __restrict__ We3T,
                     u16* __restrict__ Wd1T, u16* __restrict__ Wd2T,
                     u16* __restrict__ emb_bf, float* __restrict__ norm2,
                     float* __restrict__ sums) {
    int b = blockIdx.x, t = threadIdx.x;
    if (b == 0 && t < 2) sums[t] = 0.f;
    if (b < 256)       { int e = b * 256 + t;          int i = e >> 8, j = e & 255; We2T[j * 256 + i] = f2bf(W_e2[e]); }
    else if (b < 384)  { int e = (b - 256) * 256 + t;  int i = e >> 7, j = e & 127; We3T[j * 256 + i] = f2bf(W_e3[e]); }
    else if (b < 512)  { int e = (b - 384) * 256 + t;  int i = e >> 8, j = e & 255; Wd1T[j * 128 + i] = f2bf(W_d1[e]); }
    else if (b < 768)  { int e = (b - 512) * 256 + t;  int i = e >> 8, j = e & 255; Wd2T[j * 256 + i] = f2bf(W_d2[e]); }
    else if (b < 1792) { int e = (b - 768) * 256 + t;  emb_bf[e] = f2bf(emb[e]); }
    else {
        int lane = t & 63, w = t >> 6;
        int r = (b - 1792) * 4 + w;
        float v0 = emb[(size_t)r * D + lane];
        float v1 = emb[(size_t)r * D + 64 + lane];
        float s = v0 * v0 + v1 * v1;
#pragma unroll
        for (int off = 32; off; off >>= 1) s += __shfl_xor(s, off);
        if (lane == 0) norm2[r] = s;
    }
}

// ---------------- encoder layer 1 (K=6), standalone at full TLP (proven ~8us)
__global__ __launch_bounds__(256) void enc1(const float* __restrict__ act, const float* __restrict__ W,
                                            const float* __restrict__ b, u16* __restrict__ h1) {
    const int gid = blockIdx.x * 256 + threadIdx.x;
    const int row = gid >> 5;
    const int col0 = (gid & 31) << 3;
    float x[A_DIM];
#pragma unroll
    for (int i = 0; i < A_DIM; i++) x[i] = act[(size_t)row * A_DIM + i];
    float s[8];
#pragma unroll
    for (int c = 0; c < 8; c++) s[c] = b[col0 + c];
#pragma unroll
    for (int i = 0; i < A_DIM; i++) {
        float xi = x[i];
#pragma unroll
        for (int c = 0; c < 8; c++) s[c] = fmaf(xi, W[i * H + col0 + c], s[c]);
    }
    uint4v o;
#pragma unroll
    for (int c2 = 0; c2 < 4; c2++)
        o[c2] = (unsigned)f2bf(fmaxf(s[c2 * 2], 0.f)) | ((unsigned)f2bf(fmaxf(s[c2 * 2 + 1], 0.f)) << 16);
    *(uint4v*)&h1[(size_t)row * H + col0] = o;
}

// ---------------- fused encoder MFMA layers: h1(global) -> h2 (LDS) -> enc -> encb
__global__ __launch_bounds__(256) void enc23_fused(
    const u16* __restrict__ h1g,
    const u16* __restrict__ We2T, const float* __restrict__ b2,
    const u16* __restrict__ We3T, const float* __restrict__ b3,
    u16* __restrict__ encb) {
    __shared__ __align__(16) u16 hA[64 * 256];   // 32KB activation tile
    __shared__ __align__(16) u16 sB[256 * 64];   // 32KB weight chunk
    const int t = threadIdx.x, lane = t & 63, w = t >> 6;
    const int l15 = lane & 15, khalf = lane >> 4;
    const int row0 = blockIdx.x * 64;
#pragma unroll
    for (int p = 0; p < 8; p++) {
        int db = (p * 256 + t) * 16;
        int r = db >> 9;
        int col = ((db & 511) ^ ((r & 7) << 4)) >> 1;
        gload_lds16(h1g + (size_t)(row0 + r) * H + col, (char*)hA + db);
    }
    int sbDst[8], sbRow[8], sbCol[8];
#pragma unroll
    for (int p = 0; p < 8; p++) {
        int db = (p * 256 + t) * 16;
        int r = db >> 7;
        sbDst[p] = db; sbRow[p] = r;
        sbCol[p] = ((db & 127) ^ ((r & 7) << 4)) >> 1;
    }
    const int kbase = khalf * 8;
    // ---- g2: h2 = relu(h1 @ We2T^T + b2), K=256
    f32x4 acc[4][4] = {};
    for (int kst = 0; kst < 4; kst++) {
        if (kst) __syncthreads();
        const int k0 = kst * 64;
#pragma unroll
        for (int p = 0; p < 8; p++)
            gload_lds16(We2T + (size_t)sbRow[p] * H + k0 + sbCol[p], (char*)sB + sbDst[p]);
        __syncthreads();
#pragma unroll
        for (int ks = 0; ks < 2; ks++) {
            const int k = k0 + ks * 32 + kbase;
            const int kb = (ks * 32 + kbase) << 1;
            short8 av[4], bv[4];
#pragma unroll
            for (int m = 0; m < 4; m++) {
                int rA = m * 16 + l15;
                av[m] = *(const short8*)((const char*)hA + ((rA << 9) | ((k << 1) ^ ((rA & 7) << 4))));
            }
#pragma unroll
            for (int n = 0; n < 4; n++) {
                int rB = w * 64 + n * 16 + l15;
                bv[n] = *(const short8*)((const char*)sB + ((rB << 7) | (kb ^ ((rB & 7) << 4))));
            }
#pragma unroll
            for (int m = 0; m < 4; m++)
#pragma unroll
                for (int n = 0; n < 4; n++)
                    acc[m][n] = __builtin_amdgcn_mfma_f32_16x16x32_bf16(av[m], bv[n], acc[m][n], 0, 0, 0);
        }
    }
    __syncthreads();
#pragma unroll
    for (int n = 0; n < 4; n++) {
        int col = w * 64 + n * 16 + l15;
        float bs = b2[col];
#pragma unroll
        for (int m = 0; m < 4; m++)
#pragma unroll
            for (int j = 0; j < 4; j++) {
                int row = m * 16 + khalf * 4 + j;
                float v = fmaxf(acc[m][n][j] + bs, 0.f);
                *(u16*)((char*)hA + ((row << 9) | ((col << 1) ^ ((row & 7) << 4)))) = f2bf(v);
            }
    }
    __syncthreads();
    // ---- g3: enc = h2 @ We3T^T + b3, K=256, out [64][128]
    f32x4 acc2[4][2] = {};
    for (int kst = 0; kst < 4; kst++) {
        if (kst) __syncthreads();
        const int k0 = kst * 64;
#pragma unroll
        for (int p = 0; p < 4; p++)
            gload_lds16(We3T + (size_t)sbRow[p] * H + k0 + sbCol[p], (char*)sB + sbDst[p]);
        __syncthreads();
#pragma unroll
        for (int ks = 0; ks < 2; ks++) {
            const int k = k0 + ks * 32 + kbase;
            const int kb = (ks * 32 + kbase) << 1;
            short8 av[4], bv[2];
#pragma unroll
            for (int m = 0; m < 4; m++) {
                int rA = m * 16 + l15;
                av[m] = *(const short8*)((const char*)hA + ((rA << 9) | ((k << 1) ^ ((rA & 7) << 4))));
            }
#pragma unroll
            for (int n = 0; n < 2; n++) {
                int rB = w * 32 + n * 16 + l15;
                bv[n] = *(const short8*)((const char*)sB + ((rB << 7) | (kb ^ ((rB & 7) << 4))));
            }
#pragma unroll
            for (int m = 0; m < 4; m++)
#pragma unroll
                for (int n = 0; n < 2; n++)
                    acc2[m][n] = __builtin_amdgcn_mfma_f32_16x16x32_bf16(av[m], bv[n], acc2[m][n], 0, 0, 0);
        }
    }
    __syncthreads();
#pragma unroll
    for (int n = 0; n < 2; n++) {
        int col = w * 32 + n * 16 + l15;
        float bs = b3[col];
#pragma unroll
        for (int m = 0; m < 4; m++)
#pragma unroll
            for (int j = 0; j < 4; j++) {
                int row = m * 16 + khalf * 4 + j;
                ((u16*)sB)[row * 128 + col] = f2bf(acc2[m][n][j] + bs);
            }
    }
    __syncthreads();
#pragma unroll
    for (int p = 0; p < 4; p++) {
        int db = (p * 256 + t) * 16;
        *(uint4v*)((char*)(encb + (size_t)row0 * D) + db) = *(const uint4v*)((const char*)sB + db);
    }
}

// ---------------- fused decoder: q gathered from L2-hot emb_bf via idx -> d1 -> d2 -> head partials
__global__ __launch_bounds__(256) void dec_fused(
    const u16* __restrict__ emb_bf, const int* __restrict__ idxbuf,
    const u16* __restrict__ Wd1T, const float* __restrict__ bd1,
    const u16* __restrict__ Wd2T, const float* __restrict__ bd2,
    const float* __restrict__ W3, float* __restrict__ part) {
    __shared__ __align__(16) u16 qA[64 * 128];   // 16KB, 256B rows, swz
    __shared__ __align__(16) u16 hA[64 * 256];   // 32KB (d1), 512B rows, swz
    __shared__ __align__(16) u16 sB[256 * 64];   // 32KB weight chunk
    __shared__ int sIdxL[64];
    const int t = threadIdx.x, lane = t & 63, w = t >> 6;
    const int l15 = lane & 15, khalf = lane >> 4;
    const int row0 = blockIdx.x * 64;
    if (t < 64) sIdxL[t] = idxbuf[row0 + t];
    __syncthreads();
    // gather q tile rows from emb_bf (512KB, L2-resident)
#pragma unroll
    for (int p = 0; p < 4; p++) {
        int db = (p * 256 + t) * 16;
        int r = db >> 8;
        int col = ((db & 255) ^ ((r & 7) << 4)) >> 1;
        gload_lds16(emb_bf + (size_t)sIdxL[r] * D + col, (char*)qA + db);
    }
    int sbDst[8], sbRow[8], sbCol[8];
#pragma unroll
    for (int p = 0; p < 8; p++) {
        int db = (p * 256 + t) * 16;
        int r = db >> 7;
        sbDst[p] = db; sbRow[p] = r;
        sbCol[p] = ((db & 127) ^ ((r & 7) << 4)) >> 1;
    }
    const int kbase = khalf * 8;
    // ---- g4: d1 = relu(q @ Wd1T^T + bd1), K=128
    f32x4 acc[4][4] = {};
    for (int kst = 0; kst < 2; kst++) {
        if (kst) __syncthreads();
        const int k0 = kst * 64;
#pragma unroll
        for (int p = 0; p < 8; p++)
            gload_lds16(Wd1T + (size_t)sbRow[p] * D + k0 + sbCol[p], (char*)sB + sbDst[p]);
        __syncthreads();
#pragma unroll
        for (int ks = 0; ks < 2; ks++) {
            const int k = k0 + ks * 32 + kbase;
            const int kb = (ks * 32 + kbase) << 1;
            short8 av[4], bv[4];
#pragma unroll
            for (int m = 0; m < 4; m++) {
                int rA = m * 16 + l15;
                av[m] = *(const short8*)((const char*)qA + ((rA << 8) | ((k << 1) ^ ((rA & 7) << 4))));
            }
#pragma unroll
            for (int n = 0; n < 4; n++) {
                int rB = w * 64 + n * 16 + l15;
                bv[n] = *(const short8*)((const char*)sB + ((rB << 7) | (kb ^ ((rB & 7) << 4))));
            }
#pragma unroll
            for (int m = 0; m < 4; m++)
#pragma unroll
                for (int n = 0; n < 4; n++)
                    acc[m][n] = __builtin_amdgcn_mfma_f32_16x16x32_bf16(av[m], bv[n], acc[m][n], 0, 0, 0);
        }
    }
#pragma unroll
    for (int n = 0; n < 4; n++) {
        int col = w * 64 + n * 16 + l15;
        float bs = bd1[col];
#pragma unroll
        for (int m = 0; m < 4; m++)
#pragma unroll
            for (int j = 0; j < 4; j++) {
                int row = m * 16 + khalf * 4 + j;
                float v = fmaxf(acc[m][n][j] + bs, 0.f);
                *(u16*)((char*)hA + ((row << 9) | ((col << 1) ^ ((row & 7) << 4)))) = f2bf(v);
            }
    }
    __syncthreads();
    // ---- g5: d2 = relu(d1 @ Wd2T^T + bd2), K=256 + fused W_d3 contraction
    f32x4 acc2[4][4] = {};
    for (int kst = 0; kst < 4; kst++) {
        if (kst) __syncthreads();
        const int k0 = kst * 64;
#pragma unroll
        for (int p = 0; p < 8; p++)
            gload_lds16(Wd2T + (size_t)sbRow[p] * H + k0 + sbCol[p], (char*)sB + sbDst[p]);
        __syncthreads();
#pragma unroll
        for (int ks = 0; ks < 2; ks++) {
            const int k = k0 + ks * 32 + kbase;
            const int kb = (ks * 32 + kbase) << 1;
            short8 av[4], bv[4];
#pragma unroll
            for (int m = 0; m < 4; m++) {
                int rA = m * 16 + l15;
                av[m] = *(const short8*)((const char*)hA + ((rA << 9) | ((k << 1) ^ ((rA & 7) << 4))));
            }
#pragma unroll
            for (int n = 0; n < 4; n++) {
                int rB = w * 64 + n * 16 + l15;
                bv[n] = *(const short8*)((const char*)sB + ((rB << 7) | (kb ^ ((rB & 7) << 4))));
            }
#pragma unroll
            for (int m = 0; m < 4; m++)
#pragma unroll
                for (int n = 0; n < 4; n++)
                    acc2[m][n] = __builtin_amdgcn_mfma_f32_16x16x32_bf16(av[m], bv[n], acc2[m][n], 0, 0, 0);
        }
    }
    float W3r[4][A_DIM], bs[4];
#pragma unroll
    for (int n = 0; n < 4; n++) {
        int col = w * 64 + n * 16 + l15;
        bs[n] = bd2[col];
#pragma unroll
        for (int j = 0; j < A_DIM; j++) W3r[n][j] = W3[col * A_DIM + j];
    }
    float* ps = part + (size_t)w * NT * A_DIM;
#pragma unroll
    for (int m = 0; m < 4; m++) {
#pragma unroll
        for (int j = 0; j < 4; j++) {
            int row = row0 + m * 16 + khalf * 4 + j;
            float p6[A_DIM] = {};
#pragma unroll
            for (int n = 0; n < 4; n++) {
                float v = fmaxf(acc2[m][n][j] + bs[n], 0.f);
#pragma unroll
                for (int jj = 0; jj < A_DIM; jj++) p6[jj] = fmaf(v, W3r[n][jj], p6[jj]);
            }
#pragma unroll
            for (int off = 1; off < 16; off <<= 1)
#pragma unroll
                for (int jj = 0; jj < A_DIM; jj++) p6[jj] += __shfl_xor(p6[jj], off);
            if (l15 == 0) {
#pragma unroll
                for (int jj = 0; jj < A_DIM; jj++) ps[(size_t)row * A_DIM + jj] = p6[jj];
            }
        }
    }
}

// ---------------- head finalize
__global__ __launch_bounds__(256) void head_final(const float* __restrict__ part, const float* __restrict__ b3,
                                                  const float* __restrict__ act, float* __restrict__ sums) {
    __shared__ float sred[4];
    const int t = threadIdx.x, lane = t & 63, w = t >> 6;
    const int n = blockIdx.x * 256 + t;
    float s = 0.f;
#pragma unroll
    for (int j = 0; j < A_DIM; j++) {
        float v = b3[j];
#pragma unroll
        for (int sl = 0; sl < 4; sl++) v += part[(size_t)sl * NT * A_DIM + (size_t)n * A_DIM + j];
        float r = tanhf(v);
        float df = r - act[(size_t)n * A_DIM + j];
        s += df * df;
    }
#pragma unroll
    for (int off = 32; off; off >>= 1) s += __shfl_xor(s, off);
    if (lane == 0) sred[w] = s;
    __syncthreads();
    if (t == 0) atomicAdd(&sums[1], sred[0] + sred[1] + sred[2] + sred[3]);
}

// ---------------- distance + argmin; vq derived from argmin keys (no gather, no q materialization)
__global__ __launch_bounds__(256) void vq_dist(const u16* __restrict__ enc_bf, const u16* __restrict__ emb_bf,
                                               const float* __restrict__ norm2,
                                               int* __restrict__ idxbuf, float* __restrict__ sums) {
    __shared__ u16 sA[128 * 128];
    __shared__ u16 sB[128 * 128];
    __shared__ float sN[KC];
    __shared__ unsigned sKey[128];
    __shared__ float svq[4];
    const int t = threadIdx.x, lane = t & 63, w = t >> 6, wr = w >> 1, wc = w & 1;
    const int row0 = blockIdx.x * 128;
    int srow[8], sdst[8], scol[8];
#pragma unroll
    for (int p = 0; p < 8; p++) {
        int db = (p * 256 + t) * 16;
        int row = db >> 8;
        srow[p] = row; sdst[p] = db;
        scol[p] = ((db & 255) ^ ((row & 7) << 4)) >> 1;
    }
#pragma unroll
    for (int p = 0; p < 8; p++) gload_lds16(enc_bf + (size_t)(row0 + srow[p]) * D + scol[p], (char*)sA + sdst[p]);
#pragma unroll
    for (int p = 0; p < 8; p++) gload_lds16(emb_bf + (size_t)srow[p] * D + scol[p], (char*)sB + sdst[p]);
    for (int i = t; i < KC; i += 256) sN[i] = norm2[i] + 1.0f;
    const int ra = wr * 64 + (lane & 15), rb = wc * 64 + (lane & 15);
    const int kbase = (lane >> 4) * 8;
    int boff[4][4];
#pragma unroll
    for (int m = 0; m < 4; m++)
#pragma unroll
        for (int ks = 0; ks < 4; ks++) {
            int rB = rb + m * 16;
            int kb = (ks * 32 + kbase) << 1;
            boff[m][ks] = (rB << 8) | (kb ^ ((rB & 7) << 4));
        }
    __syncthreads();
    short8 av[4][4];
#pragma unroll
    for (int m = 0; m < 4; m++)
#pragma unroll
        for (int ks = 0; ks < 4; ks++) {
            int rA = ra + m * 16;
            int kb = (ks * 32 + kbase) << 1;
            av[m][ks] = *(const short8*)((const char*)sA + ((rA << 8) | (kb ^ ((rA & 7) << 4))));
        }
    unsigned minKey[4][4];
#pragma unroll
    for (int m = 0; m < 4; m++)
#pragma unroll
        for (int j = 0; j < 4; j++) minKey[m][j] = 0xFFFFFFFFu;
    for (int ch = 0; ch < 16; ch++) {
        if (ch) {
            __syncthreads();
            const u16* src = emb_bf + (size_t)ch * 128 * D;
#pragma unroll
            for (int p = 0; p < 8; p++) gload_lds16(src + (size_t)srow[p] * D + scol[p], (char*)sB + sdst[p]);
            __syncthreads();
        }
        f32x4 acc[4][4] = {};
#pragma unroll
        for (int ks = 0; ks < 4; ks++) {
            short8 bv[4];
#pragma unroll
            for (int n = 0; n < 4; n++) bv[n] = *(const short8*)((const char*)sB + boff[n][ks]);
#pragma unroll
            for (int m = 0; m < 4; m++)
#pragma unroll
                for (int n = 0; n < 4; n++)
                    acc[m][n] = __builtin_amdgcn_mfma_f32_16x16x32_bf16(av[m][ks], bv[n], acc[m][n], 0, 0, 0);
        }
#pragma unroll
        for (int n = 0; n < 4; n++) {
            int k = ch * 128 + rb + n * 16;
            float nn = sN[k];
#pragma unroll
            for (int m = 0; m < 4; m++)
#pragma unroll
                for (int j = 0; j < 4; j++) {
                    float c = fmaf(acc[m][n][j], -2.f, nn);   // 1 + ||emb||^2 - 2*dot (>0)
                    unsigned key = (__float_as_uint(c) & 0xFFFFF800u) | (unsigned)k;
                    minKey[m][j] = min(minKey[m][j], key);
                }
        }
    }
#pragma unroll
    for (int off = 1; off < 16; off <<= 1) {
#pragma unroll
        for (int m = 0; m < 4; m++)
#pragma unroll
            for (int j = 0; j < 4; j++)
                minKey[m][j] = min(minKey[m][j], (unsigned)__shfl_xor((int)minKey[m][j], off));
    }
    __syncthreads();
    if (wc == 0 && (lane & 15) == 0) {
#pragma unroll
        for (int m = 0; m < 4; m++)
#pragma unroll
            for (int j = 0; j < 4; j++) {
                int row = wr * 64 + m * 16 + (lane >> 4) * 4 + j;
                sKey[row] = minKey[m][j];
            }
    }
    __syncthreads();
    if (wc == 1 && (lane & 15) == 0) {
#pragma unroll
        for (int m = 0; m < 4; m++)
#pragma unroll
            for (int j = 0; j < 4; j++) {
                int row = wr * 64 + m * 16 + (lane >> 4) * 4 + j;
                if (minKey[m][j] < sKey[row]) sKey[row] = minKey[m][j];
            }
    }
    __syncthreads();
    // vq partial: sum_rows (c_trunc - 1) + sum of all enc^2 elements (= sum_rows ||q-enc||^2)
    float vql = 0.f;
    if (t < 128) {
        unsigned sk = sKey[t];
        idxbuf[row0 + t] = (int)(sk & 0x7FFu);
        vql = __uint_as_float(sk & 0xFFFFF800u) - 1.0f;
    }
#pragma unroll
    for (int i = 0; i < 8; i++) {
        short8 v = *(const short8*)((const char*)sA + i * 4096 + t * 16);
#pragma unroll
        for (int j = 0; j < 8; j++) { float e = bf2f((u16)v[j]); vql = fmaf(e, e, vql); }
    }
#pragma unroll
    for (int off = 32; off; off >>= 1) vql += __shfl_xor(vql, off);
    if (lane == 0) svq[w] = vql;
    __syncthreads();
    if (t == 0) atomicAdd(&sums[0], svq[0] + svq[1] + svq[2] + svq[3]);
}

// ---------------- OUTPUT IS FLOAT32 ----------------
__global__ void finalize(const float* __restrict__ sums, float* __restrict__ out) {
    if (threadIdx.x == 0) {
        float vq = 1.25f * sums[0] / (float)(NT * D);
        float rec = sums[1] / (float)(NT * A_DIM);
        out[0] = rec + vq;
        out[1] = rec;
        out[2] = vq;
    }
}

extern "C" void kernel_launch(void* const* d_in, const int* in_sizes, int n_in,
                              void* d_out, int out_size, void* d_ws, size_t ws_size,
                              hipStream_t stream) {
    const float* action = (const float*)d_in[0];
    const float* W_e1 = (const float*)d_in[1];
    const float* b_e1 = (const float*)d_in[2];
    const float* W_e2 = (const float*)d_in[3];
    const float* b_e2 = (const float*)d_in[4];
    const float* W_e3 = (const float*)d_in[5];
    const float* b_e3 = (const float*)d_in[6];
    const float* emb  = (const float*)d_in[7];
    const float* W_d1 = (const float*)d_in[8];
    const float* b_d1 = (const float*)d_in[9];
    const float* W_d2 = (const float*)d_in[10];
    const float* b_d2 = (const float*)d_in[11];
    const float* W_d3 = (const float*)d_in[12];
    const float* b_d3 = (const float*)d_in[13];

    char* ws = (char*)d_ws;
    float* sums  = (float*)ws;                  // 256 B  [0]=vq_sum [1]=rec_sum
    float* norm2 = (float*)(ws + 256);          // 8 KB
    u16* We2T   = (u16*)(ws + 8448);            // 128 KB  [256][256]
    u16* We3T   = (u16*)(ws + 139520);          // 64 KB   [128][256]
    u16* Wd1T   = (u16*)(ws + 205056);          // 64 KB   [256][128]
    u16* Wd2T   = (u16*)(ws + 270592);          // 128 KB  [256][256]
    u16* emb_bf = (u16*)(ws + 401664);          // 512 KB  [2048][128]
    u16* h1     = (u16*)(ws + 925952);                   // 32 MB [NT][256]
    float* part = (float*)(ws + 925952 + 33554432);      // 6.3 MB (old h2 slab)
    u16* encb   = (u16*)(ws + 925952 + 67108864);        // 16 MB [NT][128]
    int* idxbuf = (int*)(ws + 925952 + 83886080);        // 256 KB [NT] (old qb slab)

    prep<<<2304, 256, 0, stream>>>(W_e2, W_e3, W_d1, W_d2, emb, We2T, We3T, Wd1T, Wd2T, emb_bf, norm2, sums);
    enc1<<<NT * 32 / 256, 256, 0, stream>>>(action, W_e1, b_e1, h1);
    enc23_fused<<<NT / 64, 256, 0, stream>>>(h1, We2T, b_e2, We3T, b_e3, encb);
    vq_dist<<<NT / 128, 256, 0, stream>>>(encb, emb_bf, norm2, idxbuf, sums);
    dec_fused<<<NT / 64, 256, 0, stream>>>(emb_bf, idxbuf, Wd1T, b_d1, Wd2T, b_d2, W_d3, part);
    head_final<<<NT / 256, 256, 0, stream>>>(part, b_d3, action, sums);
    finalize<<<1, 64, 0, stream>>>(sums, (float*)d_out);
}

// Round 14
// 142.774 us; speedup vs baseline: 1.1003x; 1.1003x over previous
//
#include <hip/hip_runtime.h>
#include <stdint.h>

typedef unsigned short u16;
typedef float f32x4 __attribute__((ext_vector_type(4)));
typedef short short8 __attribute__((ext_vector_type(8)));
typedef unsigned uint4v __attribute__((ext_vector_type(4)));

enum { NT = 65536, KC = 2048, D = 128, H = 256, A_DIM = 6 };

__device__ __forceinline__ u16 f2bf(float f) {
    union { float f; unsigned u; } x; x.f = f;
    unsigned r = x.u + 0x7FFFu + ((x.u >> 16) & 1u);
    return (u16)(r >> 16);
}
__device__ __forceinline__ float bf2f(u16 u) {
    union { unsigned u; float f; } x; x.u = ((unsigned)u) << 16;
    return x.f;
}

typedef __attribute__((address_space(1))) void gvoid;
typedef __attribute__((address_space(3))) void lvoid;
__device__ __forceinline__ void gload_lds16(const void* g, void* l) {
    __builtin_amdgcn_global_load_lds((gvoid*)g, (lvoid*)l, 16, 0, 0);
}

// ---------------- prep: transpose+cast weights to bf16 [N][K], cast emb, emb row norms, zero sums
__global__ void prep(const float* __restrict__ W_e2, const float* __restrict__ W_e3,
                     const float* __restrict__ W_d1, const float* __restrict__ W_d2,
                     const float* __restrict__ emb,
                     u16* __restrict__ We2T, u16* __restrict__ We3T,
                     u16* __restrict__ Wd1T, u16* __restrict__ Wd2T,
                     u16* __restrict__ emb_bf, float* __restrict__ norm2,
                     float* __restrict__ sums) {
    int b = blockIdx.x, t = threadIdx.x;
    if (b == 0 && t < 2) sums[t] = 0.f;
    if (b < 256)       { int e = b * 256 + t;          int i = e >> 8, j = e & 255; We2T[j * 256 + i] = f2bf(W_e2[e]); }
    else if (b < 384)  { int e = (b - 256) * 256 + t;  int i = e >> 7, j = e & 127; We3T[j * 256 + i] = f2bf(W_e3[e]); }
    else if (b < 512)  { int e = (b - 384) * 256 + t;  int i = e >> 8, j = e & 255; Wd1T[j * 128 + i] = f2bf(W_d1[e]); }
    else if (b < 768)  { int e = (b - 512) * 256 + t;  int i = e >> 8, j = e & 255; Wd2T[j * 256 + i] = f2bf(W_d2[e]); }
    else if (b < 1792) { int e = (b - 768) * 256 + t;  emb_bf[e] = f2bf(emb[e]); }
    else {
        int lane = t & 63, w = t >> 6;
        int r = (b - 1792) * 4 + w;
        float v0 = emb[(size_t)r * D + lane];
        float v1 = emb[(size_t)r * D + 64 + lane];
        float s = v0 * v0 + v1 * v1;
#pragma unroll
        for (int off = 32; off; off >>= 1) s += __shfl_xor(s, off);
        if (lane == 0) norm2[r] = s;
    }
}

// ---------------- encoder layer 1 (K=6), standalone at full TLP (proven ~8us)
__global__ __launch_bounds__(256) void enc1(const float* __restrict__ act, const float* __restrict__ W,
                                            const float* __restrict__ b, u16* __restrict__ h1) {
    const int gid = blockIdx.x * 256 + threadIdx.x;
    const int row = gid >> 5;
    const int col0 = (gid & 31) << 3;
    float x[A_DIM];
#pragma unroll
    for (int i = 0; i < A_DIM; i++) x[i] = act[(size_t)row * A_DIM + i];
    float s[8];
#pragma unroll
    for (int c = 0; c < 8; c++) s[c] = b[col0 + c];
#pragma unroll
    for (int i = 0; i < A_DIM; i++) {
        float xi = x[i];
#pragma unroll
        for (int c = 0; c < 8; c++) s[c] = fmaf(xi, W[i * H + col0 + c], s[c]);
    }
    uint4v o;
#pragma unroll
    for (int c2 = 0; c2 < 4; c2++)
        o[c2] = (unsigned)f2bf(fmaxf(s[c2 * 2], 0.f)) | ((unsigned)f2bf(fmaxf(s[c2 * 2 + 1], 0.f)) << 16);
    *(uint4v*)&h1[(size_t)row * H + col0] = o;
}

// ---------------- fused encoder MFMA layers: h1(global) -> h2 (LDS) -> enc -> encb
__global__ __launch_bounds__(256) void enc23_fused(
    const u16* __restrict__ h1g,
    const u16* __restrict__ We2T, const float* __restrict__ b2,
    const u16* __restrict__ We3T, const float* __restrict__ b3,
    u16* __restrict__ encb) {
    __shared__ __align__(16) u16 hA[64 * 256];   // 32KB activation tile
    __shared__ __align__(16) u16 sB[256 * 64];   // 32KB weight chunk
    const int t = threadIdx.x, lane = t & 63, w = t >> 6;
    const int l15 = lane & 15, khalf = lane >> 4;
    const int row0 = blockIdx.x * 64;
#pragma unroll
    for (int p = 0; p < 8; p++) {
        int db = (p * 256 + t) * 16;
        int r = db >> 9;
        int col = ((db & 511) ^ ((r & 7) << 4)) >> 1;
        gload_lds16(h1g + (size_t)(row0 + r) * H + col, (char*)hA + db);
    }
    int sbDst[8], sbRow[8], sbCol[8];
#pragma unroll
    for (int p = 0; p < 8; p++) {
        int db = (p * 256 + t) * 16;
        int r = db >> 7;
        sbDst[p] = db; sbRow[p] = r;
        sbCol[p] = ((db & 127) ^ ((r & 7) << 4)) >> 1;
    }
    const int kbase = khalf * 8;
    // ---- g2: h2 = relu(h1 @ We2T^T + b2), K=256
    f32x4 acc[4][4] = {};
    for (int kst = 0; kst < 4; kst++) {
        if (kst) __syncthreads();
        const int k0 = kst * 64;
#pragma unroll
        for (int p = 0; p < 8; p++)
            gload_lds16(We2T + (size_t)sbRow[p] * H + k0 + sbCol[p], (char*)sB + sbDst[p]);
        __syncthreads();
#pragma unroll
        for (int ks = 0; ks < 2; ks++) {
            const int k = k0 + ks * 32 + kbase;
            const int kb = (ks * 32 + kbase) << 1;
            short8 av[4], bv[4];
#pragma unroll
            for (int m = 0; m < 4; m++) {
                int rA = m * 16 + l15;
                av[m] = *(const short8*)((const char*)hA + ((rA << 9) | ((k << 1) ^ ((rA & 7) << 4))));
            }
#pragma unroll
            for (int n = 0; n < 4; n++) {
                int rB = w * 64 + n * 16 + l15;
                bv[n] = *(const short8*)((const char*)sB + ((rB << 7) | (kb ^ ((rB & 7) << 4))));
            }
#pragma unroll
            for (int m = 0; m < 4; m++)
#pragma unroll
                for (int n = 0; n < 4; n++)
                    acc[m][n] = __builtin_amdgcn_mfma_f32_16x16x32_bf16(av[m], bv[n], acc[m][n], 0, 0, 0);
        }
    }
    __syncthreads();
#pragma unroll
    for (int n = 0; n < 4; n++) {
        int col = w * 64 + n * 16 + l15;
        float bs = b2[col];
#pragma unroll
        for (int m = 0; m < 4; m++)
#pragma unroll
            for (int j = 0; j < 4; j++) {
                int row = m * 16 + khalf * 4 + j;
                float v = fmaxf(acc[m][n][j] + bs, 0.f);
                *(u16*)((char*)hA + ((row << 9) | ((col << 1) ^ ((row & 7) << 4)))) = f2bf(v);
            }
    }
    __syncthreads();
    // ---- g3: enc = h2 @ We3T^T + b3, K=256, out [64][128]
    f32x4 acc2[4][2] = {};
    for (int kst = 0; kst < 4; kst++) {
        if (kst) __syncthreads();
        const int k0 = kst * 64;
#pragma unroll
        for (int p = 0; p < 4; p++)
            gload_lds16(We3T + (size_t)sbRow[p] * H + k0 + sbCol[p], (char*)sB + sbDst[p]);
        __syncthreads();
#pragma unroll
        for (int ks = 0; ks < 2; ks++) {
            const int k = k0 + ks * 32 + kbase;
            const int kb = (ks * 32 + kbase) << 1;
            short8 av[4], bv[2];
#pragma unroll
            for (int m = 0; m < 4; m++) {
                int rA = m * 16 + l15;
                av[m] = *(const short8*)((const char*)hA + ((rA << 9) | ((k << 1) ^ ((rA & 7) << 4))));
            }
#pragma unroll
            for (int n = 0; n < 2; n++) {
                int rB = w * 32 + n * 16 + l15;
                bv[n] = *(const short8*)((const char*)sB + ((rB << 7) | (kb ^ ((rB & 7) << 4))));
            }
#pragma unroll
            for (int m = 0; m < 4; m++)
#pragma unroll
                for (int n = 0; n < 2; n++)
                    acc2[m][n] = __builtin_amdgcn_mfma_f32_16x16x32_bf16(av[m], bv[n], acc2[m][n], 0, 0, 0);
        }
    }
    __syncthreads();
#pragma unroll
    for (int n = 0; n < 2; n++) {
        int col = w * 32 + n * 16 + l15;
        float bs = b3[col];
#pragma unroll
        for (int m = 0; m < 4; m++)
#pragma unroll
            for (int j = 0; j < 4; j++) {
                int row = m * 16 + khalf * 4 + j;
                ((u16*)sB)[row * 128 + col] = f2bf(acc2[m][n][j] + bs);
            }
    }
    __syncthreads();
#pragma unroll
    for (int p = 0; p < 4; p++) {
        int db = (p * 256 + t) * 16;
        *(uint4v*)((char*)(encb + (size_t)row0 * D) + db) = *(const uint4v*)((const char*)sB + db);
    }
}

// ---------------- fused decoder: q gathered from L2-hot emb_bf via idx -> d1 -> d2 -> head partials
// LDS exactly 80KB (qA+hA+sB) -> 2 blocks/CU; idx loaded per-lane (broadcast), no sIdxL.
__global__ __launch_bounds__(256) void dec_fused(
    const u16* __restrict__ emb_bf, const int* __restrict__ idxbuf,
    const u16* __restrict__ Wd1T, const float* __restrict__ bd1,
    const u16* __restrict__ Wd2T, const float* __restrict__ bd2,
    const float* __restrict__ W3, float* __restrict__ part) {
    __shared__ __align__(16) u16 qA[64 * 128];   // 16KB, 256B rows, swz
    __shared__ __align__(16) u16 hA[64 * 256];   // 32KB (d1), 512B rows, swz
    __shared__ __align__(16) u16 sB[256 * 64];   // 32KB weight chunk
    const int t = threadIdx.x, lane = t & 63, w = t >> 6;
    const int l15 = lane & 15, khalf = lane >> 4;
    const int row0 = blockIdx.x * 64;
    // gather q tile rows from emb_bf (512KB, L2-resident); r = p*16 + (t>>4), idx broadcast across 16 lanes
#pragma unroll
    for (int p = 0; p < 4; p++) {
        int db = (p * 256 + t) * 16;
        int r = (p << 4) + (t >> 4);
        int col = ((db & 255) ^ ((r & 7) << 4)) >> 1;
        int kidx = idxbuf[row0 + r];
        gload_lds16(emb_bf + (size_t)kidx * D + col, (char*)qA + db);
    }
    int sbDst[8], sbRow[8], sbCol[8];
#pragma unroll
    for (int p = 0; p < 8; p++) {
        int db = (p * 256 + t) * 16;
        int r = db >> 7;
        sbDst[p] = db; sbRow[p] = r;
        sbCol[p] = ((db & 127) ^ ((r & 7) << 4)) >> 1;
    }
    const int kbase = khalf * 8;
    // ---- g4: d1 = relu(q @ Wd1T^T + bd1), K=128
    f32x4 acc[4][4] = {};
    for (int kst = 0; kst < 2; kst++) {
        if (kst) __syncthreads();
        const int k0 = kst * 64;
#pragma unroll
        for (int p = 0; p < 8; p++)
            gload_lds16(Wd1T + (size_t)sbRow[p] * D + k0 + sbCol[p], (char*)sB + sbDst[p]);
        __syncthreads();                   // drains qA gather too on kst=0
#pragma unroll
        for (int ks = 0; ks < 2; ks++) {
            const int k = k0 + ks * 32 + kbase;
            const int kb = (ks * 32 + kbase) << 1;
            short8 av[4], bv[4];
#pragma unroll
            for (int m = 0; m < 4; m++) {
                int rA = m * 16 + l15;
                av[m] = *(const short8*)((const char*)qA + ((rA << 8) | ((k << 1) ^ ((rA & 7) << 4))));
            }
#pragma unroll
            for (int n = 0; n < 4; n++) {
                int rB = w * 64 + n * 16 + l15;
                bv[n] = *(const short8*)((const char*)sB + ((rB << 7) | (kb ^ ((rB & 7) << 4))));
            }
#pragma unroll
            for (int m = 0; m < 4; m++)
#pragma unroll
                for (int n = 0; n < 4; n++)
                    acc[m][n] = __builtin_amdgcn_mfma_f32_16x16x32_bf16(av[m], bv[n], acc[m][n], 0, 0, 0);
        }
    }
#pragma unroll
    for (int n = 0; n < 4; n++) {
        int col = w * 64 + n * 16 + l15;
        float bs = bd1[col];
#pragma unroll
        for (int m = 0; m < 4; m++)
#pragma unroll
            for (int j = 0; j < 4; j++) {
                int row = m * 16 + khalf * 4 + j;
                float v = fmaxf(acc[m][n][j] + bs, 0.f);
                *(u16*)((char*)hA + ((row << 9) | ((col << 1) ^ ((row & 7) << 4)))) = f2bf(v);
            }
    }
    __syncthreads();
    // ---- g5: d2 = relu(d1 @ Wd2T^T + bd2), K=256 + fused W_d3 contraction
    f32x4 acc2[4][4] = {};
    for (int kst = 0; kst < 4; kst++) {
        if (kst) __syncthreads();
        const int k0 = kst * 64;
#pragma unroll
        for (int p = 0; p < 8; p++)
            gload_lds16(Wd2T + (size_t)sbRow[p] * H + k0 + sbCol[p], (char*)sB + sbDst[p]);
        __syncthreads();
#pragma unroll
        for (int ks = 0; ks < 2; ks++) {
            const int k = k0 + ks * 32 + kbase;
            const int kb = (ks * 32 + kbase) << 1;
            short8 av[4], bv[4];
#pragma unroll
            for (int m = 0; m < 4; m++) {
                int rA = m * 16 + l15;
                av[m] = *(const short8*)((const char*)hA + ((rA << 9) | ((k << 1) ^ ((rA & 7) << 4))));
            }
#pragma unroll
            for (int n = 0; n < 4; n++) {
                int rB = w * 64 + n * 16 + l15;
                bv[n] = *(const short8*)((const char*)sB + ((rB << 7) | (kb ^ ((rB & 7) << 4))));
            }
#pragma unroll
            for (int m = 0; m < 4; m++)
#pragma unroll
                for (int n = 0; n < 4; n++)
                    acc2[m][n] = __builtin_amdgcn_mfma_f32_16x16x32_bf16(av[m], bv[n], acc2[m][n], 0, 0, 0);
        }
    }
    float W3r[4][A_DIM], bs[4];
#pragma unroll
    for (int n = 0; n < 4; n++) {
        int col = w * 64 + n * 16 + l15;
        bs[n] = bd2[col];
#pragma unroll
        for (int j = 0; j < A_DIM; j++) W3r[n][j] = W3[col * A_DIM + j];
    }
    float* ps = part + (size_t)w * NT * A_DIM;
#pragma unroll
    for (int m = 0; m < 4; m++) {
#pragma unroll
        for (int j = 0; j < 4; j++) {
            int row = row0 + m * 16 + khalf * 4 + j;
            float p6[A_DIM] = {};
#pragma unroll
            for (int n = 0; n < 4; n++) {
                float v = fmaxf(acc2[m][n][j] + bs[n], 0.f);
#pragma unroll
                for (int jj = 0; jj < A_DIM; jj++) p6[jj] = fmaf(v, W3r[n][jj], p6[jj]);
            }
#pragma unroll
            for (int off = 1; off < 16; off <<= 1)
#pragma unroll
                for (int jj = 0; jj < A_DIM; jj++) p6[jj] += __shfl_xor(p6[jj], off);
            if (l15 == 0) {
#pragma unroll
                for (int jj = 0; jj < A_DIM; jj++) ps[(size_t)row * A_DIM + jj] = p6[jj];
            }
        }
    }
}

// ---------------- head finalize
__global__ __launch_bounds__(256) void head_final(const float* __restrict__ part, const float* __restrict__ b3,
                                                  const float* __restrict__ act, float* __restrict__ sums) {
    __shared__ float sred[4];
    const int t = threadIdx.x, lane = t & 63, w = t >> 6;
    const int n = blockIdx.x * 256 + t;
    float s = 0.f;
#pragma unroll
    for (int j = 0; j < A_DIM; j++) {
        float v = b3[j];
#pragma unroll
        for (int sl = 0; sl < 4; sl++) v += part[(size_t)sl * NT * A_DIM + (size_t)n * A_DIM + j];
        float r = tanhf(v);
        float df = r - act[(size_t)n * A_DIM + j];
        s += df * df;
    }
#pragma unroll
    for (int off = 32; off; off >>= 1) s += __shfl_xor(s, off);
    if (lane == 0) sred[w] = s;
    __syncthreads();
    if (t == 0) atomicAdd(&sums[1], sred[0] + sred[1] + sred[2] + sred[3]);
}

// ---------------- distance + argmin; vq derived from argmin keys (no gather, no q materialization)
__global__ __launch_bounds__(256) void vq_dist(const u16* __restrict__ enc_bf, const u16* __restrict__ emb_bf,
                                               const float* __restrict__ norm2,
                                               int* __restrict__ idxbuf, float* __restrict__ sums) {
    __shared__ u16 sA[128 * 128];
    __shared__ u16 sB[128 * 128];
    __shared__ float sN[KC];
    __shared__ unsigned sKey[128];
    __shared__ float svq[4];
    const int t = threadIdx.x, lane = t & 63, w = t >> 6, wr = w >> 1, wc = w & 1;
    const int row0 = blockIdx.x * 128;
    int srow[8], sdst[8], scol[8];
#pragma unroll
    for (int p = 0; p < 8; p++) {
        int db = (p * 256 + t) * 16;
        int row = db >> 8;
        srow[p] = row; sdst[p] = db;
        scol[p] = ((db & 255) ^ ((row & 7) << 4)) >> 1;
    }
#pragma unroll
    for (int p = 0; p < 8; p++) gload_lds16(enc_bf + (size_t)(row0 + srow[p]) * D + scol[p], (char*)sA + sdst[p]);
#pragma unroll
    for (int p = 0; p < 8; p++) gload_lds16(emb_bf + (size_t)srow[p] * D + scol[p], (char*)sB + sdst[p]);
    for (int i = t; i < KC; i += 256) sN[i] = norm2[i] + 1.0f;
    const int ra = wr * 64 + (lane & 15), rb = wc * 64 + (lane & 15);
    const int kbase = (lane >> 4) * 8;
    int boff[4][4];
#pragma unroll
    for (int m = 0; m < 4; m++)
#pragma unroll
        for (int ks = 0; ks < 4; ks++) {
            int rB = rb + m * 16;
            int kb = (ks * 32 + kbase) << 1;
            boff[m][ks] = (rB << 8) | (kb ^ ((rB & 7) << 4));
        }
    __syncthreads();
    short8 av[4][4];
#pragma unroll
    for (int m = 0; m < 4; m++)
#pragma unroll
        for (int ks = 0; ks < 4; ks++) {
            int rA = ra + m * 16;
            int kb = (ks * 32 + kbase) << 1;
            av[m][ks] = *(const short8*)((const char*)sA + ((rA << 8) | (kb ^ ((rA & 7) << 4))));
        }
    unsigned minKey[4][4];
#pragma unroll
    for (int m = 0; m < 4; m++)
#pragma unroll
        for (int j = 0; j < 4; j++) minKey[m][j] = 0xFFFFFFFFu;
    for (int ch = 0; ch < 16; ch++) {
        if (ch) {
            __syncthreads();
            const u16* src = emb_bf + (size_t)ch * 128 * D;
#pragma unroll
            for (int p = 0; p < 8; p++) gload_lds16(src + (size_t)srow[p] * D + scol[p], (char*)sB + sdst[p]);
            __syncthreads();
        }
        f32x4 acc[4][4] = {};
#pragma unroll
        for (int ks = 0; ks < 4; ks++) {
            short8 bv[4];
#pragma unroll
            for (int n = 0; n < 4; n++) bv[n] = *(const short8*)((const char*)sB + boff[n][ks]);
#pragma unroll
            for (int m = 0; m < 4; m++)
#pragma unroll
                for (int n = 0; n < 4; n++)
                    acc[m][n] = __builtin_amdgcn_mfma_f32_16x16x32_bf16(av[m][ks], bv[n], acc[m][n], 0, 0, 0);
        }
#pragma unroll
        for (int n = 0; n < 4; n++) {
            int k = ch * 128 + rb + n * 16;
            float nn = sN[k];
#pragma unroll
            for (int m = 0; m < 4; m++)
#pragma unroll
                for (int j = 0; j < 4; j++) {
                    float c = fmaf(acc[m][n][j], -2.f, nn);   // 1 + ||emb||^2 - 2*dot (>0)
                    unsigned key = (__float_as_uint(c) & 0xFFFFF800u) | (unsigned)k;
                    minKey[m][j] = min(minKey[m][j], key);
                }
        }
    }
#pragma unroll
    for (int off = 1; off < 16; off <<= 1) {
#pragma unroll
        for (int m = 0; m < 4; m++)
#pragma unroll
            for (int j = 0; j < 4; j++)
                minKey[m][j] = min(minKey[m][j], (unsigned)__shfl_xor((int)minKey[m][j], off));
    }
    __syncthreads();
    if (wc == 0 && (lane & 15) == 0) {
#pragma unroll
        for (int m = 0; m < 4; m++)
#pragma unroll
            for (int j = 0; j < 4; j++) {
                int row = wr * 64 + m * 16 + (lane >> 4) * 4 + j;
                sKey[row] = minKey[m][j];
            }
    }
    __syncthreads();
    if (wc == 1 && (lane & 15) == 0) {
#pragma unroll
        for (int m = 0; m < 4; m++)
#pragma unroll
            for (int j = 0; j < 4; j++) {
                int row = wr * 64 + m * 16 + (lane >> 4) * 4 + j;
                if (minKey[m][j] < sKey[row]) sKey[row] = minKey[m][j];
            }
    }
    __syncthreads();
    // vq partial: sum_rows (c_trunc - 1) + sum of all enc^2 elements (= sum_rows ||q-enc||^2)
    float vql = 0.f;
    if (t < 128) {
        unsigned sk = sKey[t];
        idxbuf[row0 + t] = (int)(sk & 0x7FFu);
        vql = __uint_as_float(sk & 0xFFFFF800u) - 1.0f;
    }
#pragma unroll
    for (int i = 0; i < 8; i++) {
        short8 v = *(const short8*)((const char*)sA + i * 4096 + t * 16);
#pragma unroll
        for (int j = 0; j < 8; j++) { float e = bf2f((u16)v[j]); vql = fmaf(e, e, vql); }
    }
#pragma unroll
    for (int off = 32; off; off >>= 1) vql += __shfl_xor(vql, off);
    if (lane == 0) svq[w] = vql;
    __syncthreads();
    if (t == 0) atomicAdd(&sums[0], svq[0] + svq[1] + svq[2] + svq[3]);
}

// ---------------- OUTPUT IS FLOAT32 ----------------
__global__ void finalize(const float* __restrict__ sums, float* __restrict__ out) {
    if (threadIdx.x == 0) {
        float vq = 1.25f * sums[0] / (float)(NT * D);
        float rec = sums[1] / (float)(NT * A_DIM);
        out[0] = rec + vq;
        out[1] = rec;
        out[2] = vq;
    }
}

extern "C" void kernel_launch(void* const* d_in, const int* in_sizes, int n_in,
                              void* d_out, int out_size, void* d_ws, size_t ws_size,
                              hipStream_t stream) {
    const float* action = (const float*)d_in[0];
    const float* W_e1 = (const float*)d_in[1];
    const float* b_e1 = (const float*)d_in[2];
    const float* W_e2 = (const float*)d_in[3];
    const float* b_e2 = (const float*)d_in[4];
    const float* W_e3 = (const float*)d_in[5];
    const float* b_e3 = (const float*)d_in[6];
    const float* emb  = (const float*)d_in[7];
    const float* W_d1 = (const float*)d_in[8];
    const float* b_d1 = (const float*)d_in[9];
    const float* W_d2 = (const float*)d_in[10];
    const float* b_d2 = (const float*)d_in[11];
    const float* W_d3 = (const float*)d_in[12];
    const float* b_d3 = (const float*)d_in[13];

    char* ws = (char*)d_ws;
    float* sums  = (float*)ws;                  // 256 B  [0]=vq_sum [1]=rec_sum
    float* norm2 = (float*)(ws + 256);          // 8 KB
    u16* We2T   = (u16*)(ws + 8448);            // 128 KB  [256][256]
    u16* We3T   = (u16*)(ws + 139520);          // 64 KB   [128][256]
    u16* Wd1T   = (u16*)(ws + 205056);          // 64 KB   [256][128]
    u16* Wd2T   = (u16*)(ws + 270592);          // 128 KB  [256][256]
    u16* emb_bf = (u16*)(ws + 401664);          // 512 KB  [2048][128]
    u16* h1     = (u16*)(ws + 925952);                   // 32 MB [NT][256]
    float* part = (float*)(ws + 925952 + 33554432);      // 6.3 MB (old h2 slab)
    u16* encb   = (u16*)(ws + 925952 + 67108864);        // 16 MB [NT][128]
    int* idxbuf = (int*)(ws + 925952 + 83886080);        // 256 KB [NT]

    prep<<<2304, 256, 0, stream>>>(W_e2, W_e3, W_d1, W_d2, emb, We2T, We3T, Wd1T, Wd2T, emb_bf, norm2, sums);
    enc1<<<NT * 32 / 256, 256, 0, stream>>>(action, W_e1, b_e1, h1);
    enc23_fused<<<NT / 64, 256, 0, stream>>>(h1, We2T, b_e2, We3T, b_e3, encb);
    vq_dist<<<NT / 128, 256, 0, stream>>>(encb, emb_bf, norm2, idxbuf, sums);
    dec_fused<<<NT / 64, 256, 0, stream>>>(emb_bf, idxbuf, Wd1T, b_d1, Wd2T, b_d2, W_d3, part);
    head_final<<<NT / 256, 256, 0, stream>>>(part, b_d3, action, sums);
    finalize<<<1, 64, 0, stream>>>(sums, (float*)d_out);
}

// Round 15
// 126.068 us; speedup vs baseline: 1.2461x; 1.1325x over previous
//
#include <hip/hip_runtime.h>
#include <stdint.h>

typedef unsigned short u16;
typedef float f32x4 __attribute__((ext_vector_type(4)));
typedef short short8 __attribute__((ext_vector_type(8)));
typedef unsigned uint4v __attribute__((ext_vector_type(4)));

enum { NT = 65536, KC = 2048, D = 128, H = 256, A_DIM = 6 };

__device__ __forceinline__ u16 f2bf(float f) {
    union { float f; unsigned u; } x; x.f = f;
    unsigned r = x.u + 0x7FFFu + ((x.u >> 16) & 1u);
    return (u16)(r >> 16);
}
__device__ __forceinline__ float bf2f(u16 u) {
    union { unsigned u; float f; } x; x.u = ((unsigned)u) << 16;
    return x.f;
}

typedef __attribute__((address_space(1))) void gvoid;
typedef __attribute__((address_space(3))) void lvoid;
__device__ __forceinline__ void gload_lds16(const void* g, void* l) {
    __builtin_amdgcn_global_load_lds((gvoid*)g, (lvoid*)l, 16, 0, 0);
}

// ---------------- prep: transpose+cast weights to bf16 [N][K], cast emb, emb row norms, zero sums
__global__ void prep(const float* __restrict__ W_e2, const float* __restrict__ W_e3,
                     const float* __restrict__ W_d1, const float* __restrict__ W_d2,
                     const float* __restrict__ emb,
                     u16* __restrict__ We2T, u16* __restrict__ We3T,
                     u16* __restrict__ Wd1T, u16* __restrict__ Wd2T,
                     u16* __restrict__ emb_bf, float* __restrict__ norm2,
                     float* __restrict__ sums) {
    int b = blockIdx.x, t = threadIdx.x;
    if (b == 0 && t < 2) sums[t] = 0.f;
    if (b < 256)       { int e = b * 256 + t;          int i = e >> 8, j = e & 255; We2T[j * 256 + i] = f2bf(W_e2[e]); }
    else if (b < 384)  { int e = (b - 256) * 256 + t;  int i = e >> 7, j = e & 127; We3T[j * 256 + i] = f2bf(W_e3[e]); }
    else if (b < 512)  { int e = (b - 384) * 256 + t;  int i = e >> 8, j = e & 255; Wd1T[j * 128 + i] = f2bf(W_d1[e]); }
    else if (b < 768)  { int e = (b - 512) * 256 + t;  int i = e >> 8, j = e & 255; Wd2T[j * 256 + i] = f2bf(W_d2[e]); }
    else if (b < 1792) { int e = (b - 768) * 256 + t;  emb_bf[e] = f2bf(emb[e]); }
    else {
        int lane = t & 63, w = t >> 6;
        int r = (b - 1792) * 4 + w;
        float v0 = emb[(size_t)r * D + lane];
        float v1 = emb[(size_t)r * D + 64 + lane];
        float s = v0 * v0 + v1 * v1;
#pragma unroll
        for (int off = 32; off; off >>= 1) s += __shfl_xor(s, off);
        if (lane == 0) norm2[r] = s;
    }
}

// ---------------- fused encoder: h1 computed in-kernel (reg-W1, no serial global chains) -> h2 -> enc -> encb
__global__ __launch_bounds__(256) void enc23_fused(
    const float* __restrict__ act, const float* __restrict__ W1, const float* __restrict__ b1,
    const u16* __restrict__ We2T, const float* __restrict__ b2,
    const u16* __restrict__ We3T, const float* __restrict__ b3,
    u16* __restrict__ encb) {
    __shared__ __align__(16) u16 hA[64 * 256];   // 32KB activation tile (512B rows, swz (row&7)<<4)
    __shared__ __align__(16) u16 sB[256 * 64];   // 32KB weight chunk
    const int t = threadIdx.x, lane = t & 63, w = t >> 6;
    const int l15 = lane & 15, khalf = lane >> 4;
    const int row0 = blockIdx.x * 64;
    int sbDst[8], sbRow[8], sbCol[8];
#pragma unroll
    for (int p = 0; p < 8; p++) {
        int db = (p * 256 + t) * 16;
        int r = db >> 7;
        sbDst[p] = db; sbRow[p] = r;
        sbCol[p] = ((db & 127) ^ ((r & 7) << 4)) >> 1;
    }
    const int kbase = khalf * 8;
    f32x4 acc[4][4] = {};
    for (int kst = 0; kst < 4; kst++) {
        if (kst == 0) {
            // issue chunk-0 weight staging, then hide its latency under the h1 VALU phase
#pragma unroll
            for (int p = 0; p < 8; p++)
                gload_lds16(We2T + (size_t)sbRow[p] * H + sbCol[p], (char*)sB + sbDst[p]);
            // ---- h1 phase: thread covers rows rbase..rbase+7 x cols col0h..col0h+7
            {
                const int col0h = (t & 31) << 3;
                const int rbase = (t >> 5) << 3;
                float W1r[A_DIM][8];
#pragma unroll
                for (int i = 0; i < A_DIM; i++) {
                    f32x4 wa = *(const f32x4*)&W1[i * H + col0h];
                    f32x4 wb = *(const f32x4*)&W1[i * H + col0h + 4];
#pragma unroll
                    for (int c = 0; c < 4; c++) { W1r[i][c] = wa[c]; W1r[i][c + 4] = wb[c]; }
                }
                float bv[8];
                {
                    f32x4 ba = *(const f32x4*)&b1[col0h];
                    f32x4 bb = *(const f32x4*)&b1[col0h + 4];
#pragma unroll
                    for (int c = 0; c < 4; c++) { bv[c] = ba[c]; bv[c + 4] = bb[c]; }
                }
#pragma unroll
                for (int r8 = 0; r8 < 8; r8++) {
                    int r = rbase + r8;
                    float x[A_DIM];
#pragma unroll
                    for (int i = 0; i < A_DIM; i++) x[i] = act[(size_t)(row0 + r) * A_DIM + i];
                    float s[8];
#pragma unroll
                    for (int c = 0; c < 8; c++) s[c] = bv[c];
#pragma unroll
                    for (int i = 0; i < A_DIM; i++) {
                        float xi = x[i];
#pragma unroll
                        for (int c = 0; c < 8; c++) s[c] = fmaf(xi, W1r[i][c], s[c]);
                    }
                    uint4v o;
#pragma unroll
                    for (int c2 = 0; c2 < 4; c2++)
                        o[c2] = (unsigned)f2bf(fmaxf(s[c2 * 2], 0.f)) | ((unsigned)f2bf(fmaxf(s[c2 * 2 + 1], 0.f)) << 16);
                    *(uint4v*)((char*)hA + ((r << 9) | ((col0h << 1) ^ ((r & 7) << 4)))) = o;
                }
            }
        } else {
            __syncthreads();           // prev chunk's readers done
            const int k0 = kst * 64;
#pragma unroll
            for (int p = 0; p < 8; p++)
                gload_lds16(We2T + (size_t)sbRow[p] * H + k0 + sbCol[p], (char*)sB + sbDst[p]);
        }
        __syncthreads();               // chunk staged (+ h1 ds_writes visible at kst==0)
        const int k0 = kst * 64;
#pragma unroll
        for (int ks = 0; ks < 2; ks++) {
            const int k = k0 + ks * 32 + kbase;
            const int kb = (ks * 32 + kbase) << 1;
            short8 av[4], bvv[4];
#pragma unroll
            for (int m = 0; m < 4; m++) {
                int rA = m * 16 + l15;
                av[m] = *(const short8*)((const char*)hA + ((rA << 9) | ((k << 1) ^ ((rA & 7) << 4))));
            }
#pragma unroll
            for (int n = 0; n < 4; n++) {
                int rB = w * 64 + n * 16 + l15;
                bvv[n] = *(const short8*)((const char*)sB + ((rB << 7) | (kb ^ ((rB & 7) << 4))));
            }
#pragma unroll
            for (int m = 0; m < 4; m++)
#pragma unroll
                for (int n = 0; n < 4; n++)
                    acc[m][n] = __builtin_amdgcn_mfma_f32_16x16x32_bf16(av[m], bvv[n], acc[m][n], 0, 0, 0);
        }
    }
    __syncthreads();
#pragma unroll
    for (int n = 0; n < 4; n++) {
        int col = w * 64 + n * 16 + l15;
        float bs = b2[col];
#pragma unroll
        for (int m = 0; m < 4; m++)
#pragma unroll
            for (int j = 0; j < 4; j++) {
                int row = m * 16 + khalf * 4 + j;
                float v = fmaxf(acc[m][n][j] + bs, 0.f);
                *(u16*)((char*)hA + ((row << 9) | ((col << 1) ^ ((row & 7) << 4)))) = f2bf(v);
            }
    }
    __syncthreads();
    // ---- g3: enc = h2 @ We3T^T + b3, K=256, out [64][128]
    f32x4 acc2[4][2] = {};
    for (int kst = 0; kst < 4; kst++) {
        if (kst) __syncthreads();
        const int k0 = kst * 64;
#pragma unroll
        for (int p = 0; p < 4; p++)
            gload_lds16(We3T + (size_t)sbRow[p] * H + k0 + sbCol[p], (char*)sB + sbDst[p]);
        __syncthreads();
#pragma unroll
        for (int ks = 0; ks < 2; ks++) {
            const int k = k0 + ks * 32 + kbase;
            const int kb = (ks * 32 + kbase) << 1;
            short8 av[4], bvv[2];
#pragma unroll
            for (int m = 0; m < 4; m++) {
                int rA = m * 16 + l15;
                av[m] = *(const short8*)((const char*)hA + ((rA << 9) | ((k << 1) ^ ((rA & 7) << 4))));
            }
#pragma unroll
            for (int n = 0; n < 2; n++) {
                int rB = w * 32 + n * 16 + l15;
                bvv[n] = *(const short8*)((const char*)sB + ((rB << 7) | (kb ^ ((rB & 7) << 4))));
            }
#pragma unroll
            for (int m = 0; m < 4; m++)
#pragma unroll
                for (int n = 0; n < 2; n++)
                    acc2[m][n] = __builtin_amdgcn_mfma_f32_16x16x32_bf16(av[m], bvv[n], acc2[m][n], 0, 0, 0);
        }
    }
    __syncthreads();
#pragma unroll
    for (int n = 0; n < 2; n++) {
        int col = w * 32 + n * 16 + l15;
        float bs = b3[col];
#pragma unroll
        for (int m = 0; m < 4; m++)
#pragma unroll
            for (int j = 0; j < 4; j++) {
                int row = m * 16 + khalf * 4 + j;
                ((u16*)sB)[row * 128 + col] = f2bf(acc2[m][n][j] + bs);
            }
    }
    __syncthreads();
#pragma unroll
    for (int p = 0; p < 4; p++) {
        int db = (p * 256 + t) * 16;
        *(uint4v*)((char*)(encb + (size_t)row0 * D) + db) = *(const uint4v*)((const char*)sB + db);
    }
}

// ---------------- fused decoder + head: q(gather) -> d1 -> d2 -> W_d3 -> tanh/MSE in-kernel
__global__ __launch_bounds__(256) void dec_fused(
    const u16* __restrict__ emb_bf, const int* __restrict__ idxbuf,
    const u16* __restrict__ Wd1T, const float* __restrict__ bd1,
    const u16* __restrict__ Wd2T, const float* __restrict__ bd2,
    const float* __restrict__ W3, const float* __restrict__ b3,
    const float* __restrict__ actg, float* __restrict__ sums) {
    __shared__ __align__(16) u16 qA[64 * 128];   // 16KB; reused as float slab[4][64][6] in epilogue
    __shared__ __align__(16) u16 hA[64 * 256];   // 32KB (d1)
    __shared__ __align__(16) u16 sB[256 * 64];   // 32KB weight chunk
    const int t = threadIdx.x, lane = t & 63, w = t >> 6;
    const int l15 = lane & 15, khalf = lane >> 4;
    const int row0 = blockIdx.x * 64;
#pragma unroll
    for (int p = 0; p < 4; p++) {
        int db = (p * 256 + t) * 16;
        int r = (p << 4) + (t >> 4);
        int col = ((db & 255) ^ ((r & 7) << 4)) >> 1;
        int kidx = idxbuf[row0 + r];
        gload_lds16(emb_bf + (size_t)kidx * D + col, (char*)qA + db);
    }
    int sbDst[8], sbRow[8], sbCol[8];
#pragma unroll
    for (int p = 0; p < 8; p++) {
        int db = (p * 256 + t) * 16;
        int r = db >> 7;
        sbDst[p] = db; sbRow[p] = r;
        sbCol[p] = ((db & 127) ^ ((r & 7) << 4)) >> 1;
    }
    const int kbase = khalf * 8;
    // ---- g4: d1 = relu(q @ Wd1T^T + bd1), K=128
    f32x4 acc[4][4] = {};
    for (int kst = 0; kst < 2; kst++) {
        if (kst) __syncthreads();
        const int k0 = kst * 64;
#pragma unroll
        for (int p = 0; p < 8; p++)
            gload_lds16(Wd1T + (size_t)sbRow[p] * D + k0 + sbCol[p], (char*)sB + sbDst[p]);
        __syncthreads();
#pragma unroll
        for (int ks = 0; ks < 2; ks++) {
            const int k = k0 + ks * 32 + kbase;
            const int kb = (ks * 32 + kbase) << 1;
            short8 av[4], bvv[4];
#pragma unroll
            for (int m = 0; m < 4; m++) {
                int rA = m * 16 + l15;
                av[m] = *(const short8*)((const char*)qA + ((rA << 8) | ((k << 1) ^ ((rA & 7) << 4))));
            }
#pragma unroll
            for (int n = 0; n < 4; n++) {
                int rB = w * 64 + n * 16 + l15;
                bvv[n] = *(const short8*)((const char*)sB + ((rB << 7) | (kb ^ ((rB & 7) << 4))));
            }
#pragma unroll
            for (int m = 0; m < 4; m++)
#pragma unroll
                for (int n = 0; n < 4; n++)
                    acc[m][n] = __builtin_amdgcn_mfma_f32_16x16x32_bf16(av[m], bvv[n], acc[m][n], 0, 0, 0);
        }
    }
#pragma unroll
    for (int n = 0; n < 4; n++) {
        int col = w * 64 + n * 16 + l15;
        float bs = bd1[col];
#pragma unroll
        for (int m = 0; m < 4; m++)
#pragma unroll
            for (int j = 0; j < 4; j++) {
                int row = m * 16 + khalf * 4 + j;
                float v = fmaxf(acc[m][n][j] + bs, 0.f);
                *(u16*)((char*)hA + ((row << 9) | ((col << 1) ^ ((row & 7) << 4)))) = f2bf(v);
            }
    }
    __syncthreads();
    // ---- g5: d2 = relu(d1 @ Wd2T^T + bd2), K=256 + fused W_d3 contraction
    f32x4 acc2[4][4] = {};
    for (int kst = 0; kst < 4; kst++) {
        if (kst) __syncthreads();
        const int k0 = kst * 64;
#pragma unroll
        for (int p = 0; p < 8; p++)
            gload_lds16(Wd2T + (size_t)sbRow[p] * H + k0 + sbCol[p], (char*)sB + sbDst[p]);
        __syncthreads();
#pragma unroll
        for (int ks = 0; ks < 2; ks++) {
            const int k = k0 + ks * 32 + kbase;
            const int kb = (ks * 32 + kbase) << 1;
            short8 av[4], bvv[4];
#pragma unroll
            for (int m = 0; m < 4; m++) {
                int rA = m * 16 + l15;
                av[m] = *(const short8*)((const char*)hA + ((rA << 9) | ((k << 1) ^ ((rA & 7) << 4))));
            }
#pragma unroll
            for (int n = 0; n < 4; n++) {
                int rB = w * 64 + n * 16 + l15;
                bvv[n] = *(const short8*)((const char*)sB + ((rB << 7) | (kb ^ ((rB & 7) << 4))));
            }
#pragma unroll
            for (int m = 0; m < 4; m++)
#pragma unroll
                for (int n = 0; n < 4; n++)
                    acc2[m][n] = __builtin_amdgcn_mfma_f32_16x16x32_bf16(av[m], bvv[n], acc2[m][n], 0, 0, 0);
        }
    }
    float W3r[4][A_DIM], bs[4];
#pragma unroll
    for (int n = 0; n < 4; n++) {
        int col = w * 64 + n * 16 + l15;
        bs[n] = bd2[col];
#pragma unroll
        for (int j = 0; j < A_DIM; j++) W3r[n][j] = W3[col * A_DIM + j];
    }
    // per-wave partials -> LDS slab (qA dead after g4)
    float* slab = (float*)qA;   // [4][64][6]
    __syncthreads();            // everyone past qA reads (already true) + slab write ordering
#pragma unroll
    for (int m = 0; m < 4; m++) {
#pragma unroll
        for (int j = 0; j < 4; j++) {
            int rowl = m * 16 + khalf * 4 + j;
            float p6[A_DIM] = {};
#pragma unroll
            for (int n = 0; n < 4; n++) {
                float v = fmaxf(acc2[m][n][j] + bs[n], 0.f);
#pragma unroll
                for (int jj = 0; jj < A_DIM; jj++) p6[jj] = fmaf(v, W3r[n][jj], p6[jj]);
            }
#pragma unroll
            for (int off = 1; off < 16; off <<= 1)
#pragma unroll
                for (int jj = 0; jj < A_DIM; jj++) p6[jj] += __shfl_xor(p6[jj], off);
            if (l15 == 0) {
#pragma unroll
                for (int jj = 0; jj < A_DIM; jj++) slab[((w << 6) + rowl) * A_DIM + jj] = p6[jj];
            }
        }
    }
    __syncthreads();
    // wave 0: sum 4 slabs, tanh, MSE vs action, block atomicAdd
    if (t < 64) {
        float s = 0.f;
        int row = row0 + t;
#pragma unroll
        for (int jj = 0; jj < A_DIM; jj++) {
            float v = b3[jj];
#pragma unroll
            for (int sl = 0; sl < 4; sl++) v += slab[((sl << 6) + t) * A_DIM + jj];
            float r = tanhf(v);
            float df = r - actg[(size_t)row * A_DIM + jj];
            s = fmaf(df, df, s);
        }
#pragma unroll
        for (int off = 32; off; off >>= 1) s += __shfl_xor(s, off);
        if (t == 0) atomicAdd(&sums[1], s);
    }
}

// ---------------- distance + argmin; vq derived from argmin keys
__global__ __launch_bounds__(256) void vq_dist(const u16* __restrict__ enc_bf, const u16* __restrict__ emb_bf,
                                               const float* __restrict__ norm2,
                                               int* __restrict__ idxbuf, float* __restrict__ sums) {
    __shared__ u16 sA[128 * 128];
    __shared__ u16 sB[128 * 128];
    __shared__ float sN[KC];
    __shared__ unsigned sKey[128];
    __shared__ float svq[4];
    const int t = threadIdx.x, lane = t & 63, w = t >> 6, wr = w >> 1, wc = w & 1;
    const int row0 = blockIdx.x * 128;
    int srow[8], sdst[8], scol[8];
#pragma unroll
    for (int p = 0; p < 8; p++) {
        int db = (p * 256 + t) * 16;
        int row = db >> 8;
        srow[p] = row; sdst[p] = db;
        scol[p] = ((db & 255) ^ ((row & 7) << 4)) >> 1;
    }
#pragma unroll
    for (int p = 0; p < 8; p++) gload_lds16(enc_bf + (size_t)(row0 + srow[p]) * D + scol[p], (char*)sA + sdst[p]);
#pragma unroll
    for (int p = 0; p < 8; p++) gload_lds16(emb_bf + (size_t)srow[p] * D + scol[p], (char*)sB + sdst[p]);
    for (int i = t; i < KC; i += 256) sN[i] = norm2[i] + 1.0f;
    const int ra = wr * 64 + (lane & 15), rb = wc * 64 + (lane & 15);
    const int kbase = (lane >> 4) * 8;
    int boff[4][4];
#pragma unroll
    for (int m = 0; m < 4; m++)
#pragma unroll
        for (int ks = 0; ks < 4; ks++) {
            int rB = rb + m * 16;
            int kb = (ks * 32 + kbase) << 1;
            boff[m][ks] = (rB << 8) | (kb ^ ((rB & 7) << 4));
        }
    __syncthreads();
    short8 av[4][4];
#pragma unroll
    for (int m = 0; m < 4; m++)
#pragma unroll
        for (int ks = 0; ks < 4; ks++) {
            int rA = ra + m * 16;
            int kb = (ks * 32 + kbase) << 1;
            av[m][ks] = *(const short8*)((const char*)sA + ((rA << 8) | (kb ^ ((rA & 7) << 4))));
        }
    unsigned minKey[4][4];
#pragma unroll
    for (int m = 0; m < 4; m++)
#pragma unroll
        for (int j = 0; j < 4; j++) minKey[m][j] = 0xFFFFFFFFu;
    for (int ch = 0; ch < 16; ch++) {
        if (ch) {
            __syncthreads();
            const u16* src = emb_bf + (size_t)ch * 128 * D;
#pragma unroll
            for (int p = 0; p < 8; p++) gload_lds16(src + (size_t)srow[p] * D + scol[p], (char*)sB + sdst[p]);
            __syncthreads();
        }
        f32x4 acc[4][4] = {};
#pragma unroll
        for (int ks = 0; ks < 4; ks++) {
            short8 bv[4];
#pragma unroll
            for (int n = 0; n < 4; n++) bv[n] = *(const short8*)((const char*)sB + boff[n][ks]);
#pragma unroll
            for (int m = 0; m < 4; m++)
#pragma unroll
                for (int n = 0; n < 4; n++)
                    acc[m][n] = __builtin_amdgcn_mfma_f32_16x16x32_bf16(av[m][ks], bv[n], acc[m][n], 0, 0, 0);
        }
#pragma unroll
        for (int n = 0; n < 4; n++) {
            int k = ch * 128 + rb + n * 16;
            float nn = sN[k];
#pragma unroll
            for (int m = 0; m < 4; m++)
#pragma unroll
                for (int j = 0; j < 4; j++) {
                    float c = fmaf(acc[m][n][j], -2.f, nn);
                    unsigned key = (__float_as_uint(c) & 0xFFFFF800u) | (unsigned)k;
                    minKey[m][j] = min(minKey[m][j], key);
                }
        }
    }
#pragma unroll
    for (int off = 1; off < 16; off <<= 1) {
#pragma unroll
        for (int m = 0; m < 4; m++)
#pragma unroll
            for (int j = 0; j < 4; j++)
                minKey[m][j] = min(minKey[m][j], (unsigned)__shfl_xor((int)minKey[m][j], off));
    }
    __syncthreads();
    if (wc == 0 && (lane & 15) == 0) {
#pragma unroll
        for (int m = 0; m < 4; m++)
#pragma unroll
        for (int j = 0; j < 4; j++) {
            int row = wr * 64 + m * 16 + (lane >> 4) * 4 + j;
            sKey[row] = minKey[m][j];
        }
    }
    __syncthreads();
    if (wc == 1 && (lane & 15) == 0) {
#pragma unroll
        for (int m = 0; m < 4; m++)
#pragma unroll
        for (int j = 0; j < 4; j++) {
            int row = wr * 64 + m * 16 + (lane >> 4) * 4 + j;
            if (minKey[m][j] < sKey[row]) sKey[row] = minKey[m][j];
        }
    }
    __syncthreads();
    float vql = 0.f;
    if (t < 128) {
        unsigned sk = sKey[t];
        idxbuf[row0 + t] = (int)(sk & 0x7FFu);
        vql = __uint_as_float(sk & 0xFFFFF800u) - 1.0f;
    }
#pragma unroll
    for (int i = 0; i < 8; i++) {
        short8 v = *(const short8*)((const char*)sA + i * 4096 + t * 16);
#pragma unroll
        for (int j = 0; j < 8; j++) { float e = bf2f((u16)v[j]); vql = fmaf(e, e, vql); }
    }
#pragma unroll
    for (int off = 32; off; off >>= 1) vql += __shfl_xor(vql, off);
    if (lane == 0) svq[w] = vql;
    __syncthreads();
    if (t == 0) atomicAdd(&sums[0], svq[0] + svq[1] + svq[2] + svq[3]);
}

// ---------------- OUTPUT IS FLOAT32 ----------------
__global__ void finalize(const float* __restrict__ sums, float* __restrict__ out) {
    if (threadIdx.x == 0) {
        float vq = 1.25f * sums[0] / (float)(NT * D);
        float rec = sums[1] / (float)(NT * A_DIM);
        out[0] = rec + vq;
        out[1] = rec;
        out[2] = vq;
    }
}

extern "C" void kernel_launch(void* const* d_in, const int* in_sizes, int n_in,
                              void* d_out, int out_size, void* d_ws, size_t ws_size,
                              hipStream_t stream) {
    const float* action = (const float*)d_in[0];
    const float* W_e1 = (const float*)d_in[1];
    const float* b_e1 = (const float*)d_in[2];
    const float* W_e2 = (const float*)d_in[3];
    const float* b_e2 = (const float*)d_in[4];
    const float* W_e3 = (const float*)d_in[5];
    const float* b_e3 = (const float*)d_in[6];
    const float* emb  = (const float*)d_in[7];
    const float* W_d1 = (const float*)d_in[8];
    const float* b_d1 = (const float*)d_in[9];
    const float* W_d2 = (const float*)d_in[10];
    const float* b_d2 = (const float*)d_in[11];
    const float* W_d3 = (const float*)d_in[12];
    const float* b_d3 = (const float*)d_in[13];

    char* ws = (char*)d_ws;
    float* sums  = (float*)ws;                  // 256 B  [0]=vq_sum [1]=rec_sum
    float* norm2 = (float*)(ws + 256);          // 8 KB
    u16* We2T   = (u16*)(ws + 8448);            // 128 KB  [256][256]
    u16* We3T   = (u16*)(ws + 139520);          // 64 KB   [128][256]
    u16* Wd1T   = (u16*)(ws + 205056);          // 64 KB   [256][128]
    u16* Wd2T   = (u16*)(ws + 270592);          // 128 KB  [256][256]
    u16* emb_bf = (u16*)(ws + 401664);          // 512 KB  [2048][128]
    u16* encb   = (u16*)(ws + 925952 + 67108864);        // 16 MB [NT][128]
    int* idxbuf = (int*)(ws + 925952 + 83886080);        // 256 KB [NT]

    prep<<<2304, 256, 0, stream>>>(W_e2, W_e3, W_d1, W_d2, emb, We2T, We3T, Wd1T, Wd2T, emb_bf, norm2, sums);
    enc23_fused<<<NT / 64, 256, 0, stream>>>(action, W_e1, b_e1, We2T, b_e2, We3T, b_e3, encb);
    vq_dist<<<NT / 128, 256, 0, stream>>>(encb, emb_bf, norm2, idxbuf, sums);
    dec_fused<<<NT / 64, 256, 0, stream>>>(emb_bf, idxbuf, Wd1T, b_d1, Wd2T, b_d2, W_d3, b_d3, action, sums);
    finalize<<<1, 64, 0, stream>>>(sums, (float*)d_out);
}